// Round 2
// baseline (191.111 us; speedup 1.0000x reference)
//
#include <hip/hip_runtime.h>

#define TT 512
#define LL 64
#define BB 16
#define NN 20
#define DTC 0.01f
#define NOISEC 1e-3f
#define LN2C 0.69314718056f
#define PSKEW 576   // lane*9+r max = 63*9+7 = 574

// ws[0..63] = rowsum(pathloss), ws[64..127] = diag(pathloss)
__global__ void prep_kernel(const float* __restrict__ pathloss, float* __restrict__ ws) {
    int l = threadIdx.x;  // 64 threads
    float s = 0.f;
    #pragma unroll
    for (int j = 0; j < LL; ++j) s += pathloss[l * LL + j];
    ws[l] = s;
    ws[LL + l] = pathloss[l * LL + l];
}

// One block per channel c = b*64 + l. 256 threads = 4 waves.
// Chain of 19 causal convolutions with time-reversed kernels (matches XLA
// cross-correlation, pad (T-1,T-1), keep out[:T]).
// qrevPad[v] (v in [0,1024)): v<512 -> 0 (triangle masking for free),
// v = 512+d -> q_n[511-d]. Stored residue-split: qr8[v&7][v>>3] so the
// per-m fresh read is stride-1 across lanes (no bank conflicts).
// The sliding window V[] uses STATIC rotated indexing (V[(r-i)&7]) so the
// fully-unrolled inner loop has zero v_mov register traffic.
__global__ __launch_bounds__(256) void outage_kernel(
    const float* __restrict__ powers,
    const float* __restrict__ ws,
    float* __restrict__ out)
{
    __shared__ float Qs[TT];            // current Q_n
    __shared__ float qr8[8][128];       // residue-split zero-padded reversed kernel
    __shared__ float partial[4][PSKEW]; // per-wave partial sums, skewed (lane*9+r)

    const int tid  = threadIdx.x;
    const int wave = tid >> 6;
    const int lane = tid & 63;
    const int c = blockIdx.x;
    const int b = c >> 6;
    const int l = c & 63;

    const float rs = ws[l];
    const float dg = ws[LL + l];
    const float dsum = rs - dg;

    // each thread owns two time indices
    const int tau0 = tid;
    const int tau1 = tid + 256;
    const float p2a = exp2f(tau0 * DTC);   // 2^{t}
    const float p2b = exp2f(tau1 * DTC);
    const float p1a = p2a - 1.f;           // 2^{t} - 1
    const float p1b = p2b - 1.f;

    // zero the padding half of qr8: flat v in [0,512) -> qr8[v&7][v>>3]
    qr8[tau0 & 7][tau0 >> 3] = 0.f;
    qr8[tau1 & 7][tau1 >> 3] = 0.f;

    // Q_0 = Q1 = 1 - exp(-(2^t - 1) * sinr_0)
    {
        float p  = powers[(b * NN + 0) * LL + l];
        float s0 = dg * p / (p * dsum + NOISEC);
        Qs[tau0] = 1.f - expf(-p1a * s0);
        Qs[tau1] = 1.f - expf(-p1b * s0);
    }
    __syncthreads();

    float lossCh = 0.f;
    if (tid == 0) {
        // 1 (RHO*D base) + power[b,0,l] (E base) + (power[b,1,l]+1)*Q_0[511]
        lossCh = 1.f + powers[(b * NN + 0) * LL + l]
               + (powers[(b * NN + 1) * LL + l] + 1.f) * Qs[TT - 1];
    }

    const int m0    = wave << 7;              // this wave's m-range start
    const int initJ = 64 - (wave << 4) + lane;

    for (int n = 1; n < NN; ++n) {
        // ---- fill reversed kernel for step n ----
        {
            float p = powers[(b * NN + n) * LL + l];
            float s = dg * p / (p * dsum + NOISEC);
            float q0 = expf(-p1a * s) * p2a * s * LN2C;
            float q1 = expf(-p1b * s) * p2b * s * LN2C;
            int v0 = 1023 - tau0;   // data region v >= 512 only; zeros persist
            int v1 = 1023 - tau1;
            qr8[v0 & 7][v0 >> 3] = q0;
            qr8[v1 & 7][v1 >> 3] = q1;
        }
        __syncthreads();

        // ---- accumulate: lane owns outputs t = 8*lane .. 8*lane+7,
        //      wave owns m in [m0, m0+128) ----
        // Invariant (static rotation): entering iteration i of block mb,
        // slot V[(x)&7] holds qrevPad[512 + 8*lane + x - (m0+mb)] for
        // x = -i .. 7-i; FMA for output r uses V[(r-i)&7]; fresh load of
        // x = -(i+1) lands in slot (7-i)&7. Self-renewing across mb blocks.
        float acc[8];
        #pragma unroll
        for (int r = 0; r < 8; ++r) acc[r] = 0.f;
        float V[8];
        #pragma unroll
        for (int s = 0; s < 8; ++s) V[s] = qr8[s][initJ];

        #pragma unroll
        for (int mb = 0; mb < 128; mb += 8) {
            const int baseJ = 63 - (wave << 4) - (mb >> 3) + lane;
            #pragma unroll
            for (int i = 0; i < 8; ++i) {
                float Qm = Qs[m0 + mb + i];           // broadcast (uniform addr)
                #pragma unroll
                for (int r = 0; r < 8; ++r)
                    acc[r] = fmaf(Qm, V[(r - i + 8) & 7], acc[r]);
                // fresh element: v = 8*lane + 511 - m; residue = 7-i (const)
                V[(7 - i) & 7] = qr8[7 - i][baseJ];
            }
        }

        #pragma unroll
        for (int r = 0; r < 8; ++r) partial[wave][lane * 9 + r] = acc[r];
        __syncthreads();

        // ---- combine partials, scale by DT, write back Q ----
        {
            const int s0i = (tau0 >> 3) * 9 + (tau0 & 7);
            const int s1i = (tau1 >> 3) * 9 + (tau1 & 7);
            float v0 = (partial[0][s0i] + partial[1][s0i])
                     + (partial[2][s0i] + partial[3][s0i]);
            float v1 = (partial[0][s1i] + partial[1][s1i])
                     + (partial[2][s1i] + partial[3][s1i]);
            Qs[tau0] = v0 * DTC;
            Qs[tau1] = v1 * DTC;
        }
        __syncthreads();

        if (tid == 0) {
            float qlast = Qs[TT - 1];
            float wgt = (n < NN - 1) ? (powers[(b * NN + n + 1) * LL + l] + 1.f)
                                     : 1.f;   // LAM term for n = 19
            lossCh += wgt * qlast;
        }
    }

    if (tid == 0) atomicAdd(out, lossCh);
}

extern "C" void kernel_launch(void* const* d_in, const int* in_sizes, int n_in,
                              void* d_out, int out_size, void* d_ws, size_t ws_size,
                              hipStream_t stream) {
    const float* pathloss = (const float*)d_in[0];
    const float* powers   = (const float*)d_in[1];
    float* outp = (float*)d_out;
    float* ws   = (float*)d_ws;

    hipMemsetAsync(d_out, 0, sizeof(float) * out_size, stream);
    prep_kernel<<<1, 64, 0, stream>>>(pathloss, ws);
    outage_kernel<<<BB * LL, 256, 0, stream>>>(powers, ws, outp);
}

// Round 3
// 180.901 us; speedup vs baseline: 1.0564x; 1.0564x over previous
//
#include <hip/hip_runtime.h>

#define TT 512
#define LL 64
#define BB 16
#define NN 20
#define DTC 0.01f
#define NOISEC 1e-3f
#define LN2C 0.69314718056f
#define PSKEW 576   // lane*9+r, max 574
#define QROW 12     // 8 data + 4 pad floats; 48B rows: 16B-aligned, even bank spread

// ws[0..63] = rowsum(pathloss), ws[64..127] = diag(pathloss)
__global__ void prep_kernel(const float* __restrict__ pathloss, float* __restrict__ ws) {
    int l = threadIdx.x;  // 64 threads
    float s = 0.f;
    #pragma unroll
    for (int j = 0; j < LL; ++j) s += pathloss[l * LL + j];
    ws[l] = s;
    ws[LL + l] = pathloss[l * LL + l];
}

// One block per channel c = b*64 + l. 256 threads = 4 waves.
// Chain of 19 causal convolutions with time-reversed kernels (matches XLA
// cross-correlation, pad (T-1,T-1), keep out[:T]).
// qrevPad[v], v in [0,1024): v<512 -> 0 (free triangle masking),
// v=512+d -> q_n[511-d]. Layout qrT[j][p] = qrevPad[8j+7-p] (descending rows):
// rows 0..63 permanently zero, rows 64..127 = data (refilled per step).
// Per 8-m block a lane's 8 fresh window values are one contiguous row ->
// 2x ds_read_b128. Row stride 48B: 16B-aligned + bank starts 12*lane mod 32
// cover all quads evenly -> conflict-free at the BW minimum (8 cyc/b128).
// Qm values read 8-at-a-time via 2x broadcast ds_read_b128.
__global__ __launch_bounds__(256) void outage_kernel(
    const float* __restrict__ powers,
    const float* __restrict__ ws,
    float* __restrict__ out)
{
    __shared__ float Qs[TT];             // current Q_n
    __shared__ float qrT[128][QROW];     // descending-row reversed kernel
    __shared__ float partial[4][PSKEW];  // per-wave partials, skewed (lane*9+r)

    const int tid  = threadIdx.x;
    const int wave = tid >> 6;
    const int lane = tid & 63;
    const int c = blockIdx.x;
    const int b = c >> 6;
    const int l = c & 63;

    const float rs = ws[l];
    const float dg = ws[LL + l];
    const float dsum = rs - dg;

    // each thread owns two time indices
    const int tau0 = tid;
    const int tau1 = tid + 256;
    const float p2a = exp2f(tau0 * DTC);   // 2^{t}
    const float p2b = exp2f(tau1 * DTC);
    const float p1a = p2a - 1.f;           // 2^{t} - 1
    const float p1b = p2b - 1.f;

    // zero rows 0..63 positions 0..7 (512 slots; zeros persist across steps)
    qrT[tid >> 3][tid & 7] = 0.f;
    qrT[(tid + 256) >> 3][(tid + 256) & 7] = 0.f;

    // Q_0 = 1 - exp(-(2^t - 1) * sinr_0)
    {
        float p  = powers[(b * NN + 0) * LL + l];
        float s0 = dg * p / (p * dsum + NOISEC);
        Qs[tau0] = 1.f - expf(-p1a * s0);
        Qs[tau1] = 1.f - expf(-p1b * s0);
    }
    __syncthreads();

    float lossCh = 0.f;
    if (tid == 0) {
        lossCh = 1.f + powers[(b * NN + 0) * LL + l]
               + (powers[(b * NN + 1) * LL + l] + 1.f) * Qs[TT - 1];
    }

    const int m0  = wave << 7;            // this wave's m-range start
    const int w16 = wave << 4;
    // fresh row j = 63 + lane - 16w - mb/8; pre-offset to mb=120 so all
    // unrolled offsets are non-negative immediates
    const float* qrow0 = &qrT[48 + lane - w16][0];
    const float* qinit = &qrT[64 + lane - w16][0];

    for (int n = 1; n < NN; ++n) {
        // ---- fill data rows (64..127) for step n: qrT[127-(t>>3)][t&7]=q(t) ----
        {
            float p = powers[(b * NN + n) * LL + l];
            float s = dg * p / (p * dsum + NOISEC);
            float q0 = expf(-p1a * s) * p2a * s * LN2C;
            float q1 = expf(-p1b * s) * p2b * s * LN2C;
            qrT[127 - (tau0 >> 3)][tau0 & 7] = q0;
            qrT[127 - (tau1 >> 3)][tau1 & 7] = q1;
        }
        __syncthreads();

        // ---- accumulate: lane owns outputs t = 8*lane..8*lane+7,
        //      wave owns m in [m0, m0+128) ----
        float acc[8];
        #pragma unroll
        for (int r = 0; r < 8; ++r) acc[r] = 0.f;

        // initial window V[x] = qrevPad[512+8*lane-m0+x] = qinit[7-x]
        float V[8];
        {
            const float4 a  = *(const float4*)(qinit);
            const float4 bb = *(const float4*)(qinit + 4);
            V[7] = a.x;  V[6] = a.y;  V[5] = a.z;  V[4] = a.w;
            V[3] = bb.x; V[2] = bb.y; V[1] = bb.z; V[0] = bb.w;
        }

        #pragma unroll
        for (int mb = 0; mb < 128; mb += 8) {
            const int off = (15 - (mb >> 3)) * QROW;
            const float4 fa = *(const float4*)(qrow0 + off);      // fresh[0..3]
            const float4 fb = *(const float4*)(qrow0 + off + 4);  // fresh[4..7]
            const float4 qa = *(const float4*)&Qs[m0 + mb];       // broadcast
            const float4 qb = *(const float4*)&Qs[m0 + mb + 4];
            const float qm[8] = {qa.x, qa.y, qa.z, qa.w, qb.x, qb.y, qb.z, qb.w};
            const float fr[8] = {fa.x, fa.y, fa.z, fa.w, fb.x, fb.y, fb.z, fb.w};
            #pragma unroll
            for (int i = 0; i < 8; ++i) {
                #pragma unroll
                for (int r = 0; r < 8; ++r)
                    acc[r] = fmaf(qm[i], V[(r - i + 8) & 7], acc[r]);
                // fresh element for x = -(i+1); lands in slot (7-i)&7
                V[(7 - i) & 7] = fr[i];
            }
        }

        #pragma unroll
        for (int r = 0; r < 8; ++r) partial[wave][lane * 9 + r] = acc[r];
        __syncthreads();

        // ---- combine partials, scale by DT, write back Q ----
        {
            const int s0i = (tau0 >> 3) * 9 + (tau0 & 7);
            const int s1i = (tau1 >> 3) * 9 + (tau1 & 7);
            float v0 = (partial[0][s0i] + partial[1][s0i])
                     + (partial[2][s0i] + partial[3][s0i]);
            float v1 = (partial[0][s1i] + partial[1][s1i])
                     + (partial[2][s1i] + partial[3][s1i]);
            Qs[tau0] = v0 * DTC;
            Qs[tau1] = v1 * DTC;
        }
        __syncthreads();

        if (tid == 0) {
            float qlast = Qs[TT - 1];
            float wgt = (n < NN - 1) ? (powers[(b * NN + n + 1) * LL + l] + 1.f)
                                     : 1.f;   // LAM term for n = 19
            lossCh += wgt * qlast;
        }
    }

    if (tid == 0) atomicAdd(out, lossCh);
}

extern "C" void kernel_launch(void* const* d_in, const int* in_sizes, int n_in,
                              void* d_out, int out_size, void* d_ws, size_t ws_size,
                              hipStream_t stream) {
    const float* pathloss = (const float*)d_in[0];
    const float* powers   = (const float*)d_in[1];
    float* outp = (float*)d_out;
    float* ws   = (float*)d_ws;

    hipMemsetAsync(d_out, 0, sizeof(float) * out_size, stream);
    prep_kernel<<<1, 64, 0, stream>>>(pathloss, ws);
    outage_kernel<<<BB * LL, 256, 0, stream>>>(powers, ws, outp);
}

// Round 4
// 175.065 us; speedup vs baseline: 1.0917x; 1.0333x over previous
//
#include <hip/hip_runtime.h>

#define TT 512
#define LL 64
#define BB 16
#define NN 20
#define DTC 0.01f
#define NOISEC 1e-3f
#define LN2C 0.69314718056f
#define QROW 12     // qrT row stride in floats (48B, 16B-aligned)
#define PP 576      // partial row stride: skewed idx max = 511 + 4*15 = 571

// ws[0..63] = rowsum(pathloss), ws[64..127] = diag(pathloss)
__global__ void prep_kernel(const float* __restrict__ pathloss, float* __restrict__ ws) {
    int l = threadIdx.x;  // 64 threads
    float s = 0.f;
    #pragma unroll
    for (int j = 0; j < LL; ++j) s += pathloss[l * LL + j];
    ws[l] = s;
    ws[LL + l] = pathloss[l * LL + l];
}

// One block per channel c = b*64 + l. 256 threads = 4 waves.
// Chain of 19 causal convolutions with time-reversed kernels.
// qrevPad[v], v in [0,1024): v<512 -> 0, v=512+d -> q_n[511-d].
// qrT[j][p] = qrevPad[8j+7-p]; rows 0..63 permanently zero, 64..127 data.
//
// NEW in R4: each lane owns 16 outputs t in [16J,16J+16) (J = lane>>1) and
// m-range [128*wave + 64*h, +64) (h = lane&1). 16-slot rotating window W,
// invariant: at global sub-step tau (m = m_start+tau), FMA for output r reads
// W[(r-tau)&15]; fresh qrevPad[512+16J-1-m] lands in slot (15-tau)&15 (the
// slot whose value died at this tau). Fresh LDS bytes per FMA are HALVED vs
// R3 (8 floats per 128 FMAs). h-pairs reduced via one shfl_xor round; the
// 4 wave partials combine through LDS as before.
__global__ __launch_bounds__(256) void outage_kernel(
    const float* __restrict__ powers,
    const float* __restrict__ ws,
    float* __restrict__ out)
{
    __shared__ float Qs[TT];             // current Q_n
    __shared__ float qrT[128][QROW];     // descending-row reversed kernel
    __shared__ float partial[4][PP];     // per-wave partials, skewed

    const int tid  = threadIdx.x;
    const int wave = tid >> 6;
    const int lane = tid & 63;
    const int c = blockIdx.x;
    const int b = c >> 6;
    const int l = c & 63;

    const float rs = ws[l];
    const float dg = ws[LL + l];
    const float dsum = rs - dg;

    // each thread owns two time indices for fill/combine phases
    const int tau0 = tid;
    const int tau1 = tid + 256;
    const float p2a = exp2f(tau0 * DTC);   // 2^{t}
    const float p2b = exp2f(tau1 * DTC);
    const float p1a = p2a - 1.f;           // 2^{t} - 1
    const float p1b = p2b - 1.f;

    // zero rows 0..63 (512 slots; zeros persist: fills touch rows 64..127 only)
    qrT[tid >> 3][tid & 7] = 0.f;
    qrT[(tid + 256) >> 3][(tid + 256) & 7] = 0.f;

    // Q_0 = 1 - exp(-(2^t - 1) * sinr_0)
    {
        float p  = powers[(b * NN + 0) * LL + l];
        float s0 = dg * p / (p * dsum + NOISEC);
        Qs[tau0] = 1.f - expf(-p1a * s0);
        Qs[tau1] = 1.f - expf(-p1b * s0);
    }
    __syncthreads();

    float lossCh = 0.f;
    if (tid == 0) {
        lossCh = 1.f + powers[(b * NN + 0) * LL + l]
               + (powers[(b * NN + 1) * LL + l] + 1.f) * Qs[TT - 1];
    }

    const int J   = lane >> 1;           // t-block index: t in [16J, 16J+16)
    const int h   = lane & 1;            // m half within the wave's 128-range
    const int ms8 = (wave << 4) + (h << 3);   // m_start/8; m_start = 8*ms8
    // window init rows R0, R0+1: R0 = 64 + 2J - ms8  (range [8,126])
    const float* qinit = &qrT[64 + (J << 1) - ms8][0];
    // fresh row for octet k is (63 + 2J - ms8 - k); pre-offset to k=7 (>=0)
    const float* qrow7 = &qrT[56 + (J << 1) - ms8][0];
    const float* qsm   = &Qs[ms8 << 3];
    // skewed partial write base: idx = 16J + 8h + 4*(J>>1)  (all quads even)
    float* pwr = &partial[wave][(J << 4) + (h << 3) + ((J >> 1) << 2)];
    const int s0i = tau0 + ((tau0 >> 5) << 2);   // skew-adjusted read idx
    const int s1i = tau1 + ((tau1 >> 5) << 2);

    for (int n = 1; n < NN; ++n) {
        // ---- fill data rows (64..127): qrT[127-(t>>3)][t&7] = q(t) ----
        {
            float p = powers[(b * NN + n) * LL + l];
            float s = dg * p / (p * dsum + NOISEC);
            float q0 = expf(-p1a * s) * p2a * s * LN2C;
            float q1 = expf(-p1b * s) * p2b * s * LN2C;
            qrT[127 - (tau0 >> 3)][tau0 & 7] = q0;
            qrT[127 - (tau1 >> 3)][tau1 & 7] = q1;
        }
        __syncthreads();

        float acc[16];
        #pragma unroll
        for (int r = 0; r < 16; ++r) acc[r] = 0.f;

        // init window W[x] = qrevPad[512+16J-m_start+x], x in [0,16):
        // row R0 gives x=7-p, row R0+1 gives x=15-p
        float W[16];
        {
            const float4 a0 = *(const float4*)(qinit);
            const float4 a1 = *(const float4*)(qinit + 4);
            const float4 a2 = *(const float4*)(qinit + QROW);
            const float4 a3 = *(const float4*)(qinit + QROW + 4);
            W[7]  = a0.x; W[6]  = a0.y; W[5]  = a0.z; W[4]  = a0.w;
            W[3]  = a1.x; W[2]  = a1.y; W[1]  = a1.z; W[0]  = a1.w;
            W[15] = a2.x; W[14] = a2.y; W[13] = a2.z; W[12] = a2.w;
            W[11] = a3.x; W[10] = a3.y; W[9]  = a3.z; W[8]  = a3.w;
        }

        #pragma unroll
        for (int k = 0; k < 8; ++k) {
            const int off = (7 - k) * QROW;
            const float4 fa = *(const float4*)(qrow7 + off);      // fresh p=0..3
            const float4 fb = *(const float4*)(qrow7 + off + 4);  // fresh p=4..7
            const float4 qa = *(const float4*)(qsm + (k << 3));   // Qm (2-addr bcast)
            const float4 qb = *(const float4*)(qsm + (k << 3) + 4);
            const float qm[8] = {qa.x, qa.y, qa.z, qa.w, qb.x, qb.y, qb.z, qb.w};
            const float fr[8] = {fa.x, fa.y, fa.z, fa.w, fb.x, fb.y, fb.z, fb.w};
            #pragma unroll
            for (int i = 0; i < 8; ++i) {
                const int tau = (k << 3) + i;
                #pragma unroll
                for (int r = 0; r < 16; ++r)
                    acc[r] = fmaf(qm[i], W[(r - tau) & 15], acc[r]);
                // fresh v = 511+16J-m_start-tau lands in the slot that just died
                W[(15 - tau) & 15] = fr[i];
            }
        }

        // ---- h-pair reduction: both lanes get full 128-m sums ----
        float sum16[16];
        #pragma unroll
        for (int u = 0; u < 16; ++u)
            sum16[u] = acc[u] + __shfl_xor(acc[u], 1, 64);
        // lane h stores its half u in [8h, 8h+8) -> 2 x b128, skewed
        {
            float o0 = h ? sum16[8]  : sum16[0];
            float o1 = h ? sum16[9]  : sum16[1];
            float o2 = h ? sum16[10] : sum16[2];
            float o3 = h ? sum16[11] : sum16[3];
            float o4 = h ? sum16[12] : sum16[4];
            float o5 = h ? sum16[13] : sum16[5];
            float o6 = h ? sum16[14] : sum16[6];
            float o7 = h ? sum16[15] : sum16[7];
            *(float4*)(pwr)     = make_float4(o0, o1, o2, o3);
            *(float4*)(pwr + 4) = make_float4(o4, o5, o6, o7);
        }
        __syncthreads();

        // ---- combine 4 wave partials, scale by DT, write back Q ----
        {
            float v0 = (partial[0][s0i] + partial[1][s0i])
                     + (partial[2][s0i] + partial[3][s0i]);
            float v1 = (partial[0][s1i] + partial[1][s1i])
                     + (partial[2][s1i] + partial[3][s1i]);
            Qs[tau0] = v0 * DTC;
            Qs[tau1] = v1 * DTC;
        }
        __syncthreads();

        if (tid == 0) {
            float qlast = Qs[TT - 1];
            float wgt = (n < NN - 1) ? (powers[(b * NN + n + 1) * LL + l] + 1.f)
                                     : 1.f;   // LAM term for n = 19
            lossCh += wgt * qlast;
        }
    }

    if (tid == 0) atomicAdd(out, lossCh);
}

extern "C" void kernel_launch(void* const* d_in, const int* in_sizes, int n_in,
                              void* d_out, int out_size, void* d_ws, size_t ws_size,
                              hipStream_t stream) {
    const float* pathloss = (const float*)d_in[0];
    const float* powers   = (const float*)d_in[1];
    float* outp = (float*)d_out;
    float* ws   = (float*)d_ws;

    hipMemsetAsync(d_out, 0, sizeof(float) * out_size, stream);
    prep_kernel<<<1, 64, 0, stream>>>(pathloss, ws);
    outage_kernel<<<BB * LL, 256, 0, stream>>>(powers, ws, outp);
}

// Round 5
// 171.248 us; speedup vs baseline: 1.1160x; 1.0223x over previous
//
#include <hip/hip_runtime.h>

#define TT 512
#define LL 64
#define BB 16
#define NN 20
#define DTC 0.01f
#define NOISEC 1e-3f
#define LN2C 0.69314718056f
#define QROW 12     // qrT row stride in floats (48B, 16B-aligned)
#define PP 544      // partial row: skewed idx max = 511 + 4*7 = 539

typedef float v2f __attribute__((ext_vector_type(2)));

// v_pk_fma_f32: d = q*w + d per 32-bit half. qh: duplicate q.half[qh] into
// both results (op_sel[0]=op_sel_hi[0]=qh). ws=1: swap w halves between the
// two results. All selects compile-time after full unroll.
__device__ __forceinline__ void pkfma(v2f& d, v2f q, v2f w, int qh, int ws) {
    if (qh == 0) {
        if (ws == 0) asm("v_pk_fma_f32 %0, %1, %2, %0 op_sel:[0,0,0] op_sel_hi:[0,1,1]" : "+v"(d) : "v"(q), "v"(w));
        else         asm("v_pk_fma_f32 %0, %1, %2, %0 op_sel:[0,1,0] op_sel_hi:[0,0,1]" : "+v"(d) : "v"(q), "v"(w));
    } else {
        if (ws == 0) asm("v_pk_fma_f32 %0, %1, %2, %0 op_sel:[1,0,0] op_sel_hi:[1,1,1]" : "+v"(d) : "v"(q), "v"(w));
        else         asm("v_pk_fma_f32 %0, %1, %2, %0 op_sel:[1,1,0] op_sel_hi:[1,0,1]" : "+v"(d) : "v"(q), "v"(w));
    }
}

// ws[0..63] = rowsum(pathloss), ws[64..127] = diag(pathloss)
__global__ void prep_kernel(const float* __restrict__ pathloss, float* __restrict__ ws) {
    int l = threadIdx.x;  // 64 threads
    float s = 0.f;
    #pragma unroll
    for (int j = 0; j < LL; ++j) s += pathloss[l * LL + j];
    ws[l] = s;
    ws[LL + l] = pathloss[l * LL + l];
}

// One block per channel. 256 threads = 4 waves. Same structure as R4
// (16 outputs/lane, 16-slot rotating window, worker (wave,h) owns 64 m's),
// but the inner loop runs on v_pk_fma_f32: acc2[r] = (out[r], out[r+8]),
// P[rho] = (W[rho], W[rho+8]); (r+8-tau)&15 = ((r-tau)&15)^8 makes every
// substep one pk_fma per pair with a static op_sel half-swap.
__global__ __launch_bounds__(256) void outage_kernel(
    const float* __restrict__ powers,
    const float* __restrict__ ws,
    float* __restrict__ out)
{
    __shared__ float Qs[TT];             // current Q_n
    __shared__ float qrT[128][QROW];     // descending-row reversed kernel
    __shared__ float partial[4][PP];     // per-wave partials, skewed

    const int tid  = threadIdx.x;
    const int wave = tid >> 6;
    const int lane = tid & 63;
    const int c = blockIdx.x;
    const int b = c >> 6;
    const int l = c & 63;

    const float rs = ws[l];
    const float dg = ws[LL + l];
    const float dsum = rs - dg;

    const int tau0 = tid;
    const int tau1 = tid + 256;
    const float p2a = exp2f(tau0 * DTC);   // 2^{t}
    const float p2b = exp2f(tau1 * DTC);
    const float p1a = p2a - 1.f;           // 2^{t} - 1
    const float p1b = p2b - 1.f;

    // zero rows 0..63 (zeros persist: fills touch rows 64..127 only)
    qrT[tid >> 3][tid & 7] = 0.f;
    qrT[(tid + 256) >> 3][(tid + 256) & 7] = 0.f;

    // Q_0 = 1 - exp(-(2^t - 1) * sinr_0)
    {
        float p  = powers[(b * NN + 0) * LL + l];
        float s0 = dg * p / (p * dsum + NOISEC);
        Qs[tau0] = 1.f - expf(-p1a * s0);
        Qs[tau1] = 1.f - expf(-p1b * s0);
    }
    __syncthreads();

    float lossCh = 0.f;
    if (tid == 0) {
        lossCh = 1.f + powers[(b * NN + 0) * LL + l]
               + (powers[(b * NN + 1) * LL + l] + 1.f) * Qs[TT - 1];
    }

    const int J   = lane >> 1;           // t-tile: t in [16J, 16J+16)
    const int h   = lane & 1;            // m half within the wave's 128-range
    const int ms8 = (wave << 4) + (h << 3);   // m_start = 8*ms8
    const float* qinit = &qrT[64 + (J << 1) - ms8][0];
    const float* qrow7 = &qrT[56 + (J << 1) - ms8][0];
    const float* qsm   = &Qs[ms8 << 3];
    // skewed partial write base: t-base bb = 16J+8h; skew 4*((bb>>5)&7)
    const int bb = (J << 4) + (h << 3);
    float* pwr = &partial[wave][bb + 4 * ((bb >> 5) & 7)];
    const int s0i = tau0 + 4 * ((tau0 >> 5) & 7);   // skew-adjusted read idx
    const int s1i = tau1 + 4 * ((tau1 >> 5) & 7);

    for (int n = 1; n < NN; ++n) {
        // ---- fill data rows (64..127): qrT[127-(t>>3)][t&7] = q(t) ----
        {
            float p = powers[(b * NN + n) * LL + l];
            float s = dg * p / (p * dsum + NOISEC);
            float q0 = expf(-p1a * s) * p2a * s * LN2C;
            float q1 = expf(-p1b * s) * p2b * s * LN2C;
            qrT[127 - (tau0 >> 3)][tau0 & 7] = q0;
            qrT[127 - (tau1 >> 3)][tau1 & 7] = q1;
        }
        __syncthreads();

        v2f A[8];   // A[r] = (out[16J+r], out[16J+r+8])
        #pragma unroll
        for (int r = 0; r < 8; ++r) A[r] = (v2f)(0.f);

        // init window W[x] = qrevPad[512+16J-m_start+x]; P[p]=(W[p],W[p+8])
        v2f P[8];
        {
            const float4 a0 = *(const float4*)(qinit);
            const float4 a1 = *(const float4*)(qinit + 4);
            const float4 a2 = *(const float4*)(qinit + QROW);
            const float4 a3 = *(const float4*)(qinit + QROW + 4);
            P[0] = (v2f){a1.w, a3.w}; P[1] = (v2f){a1.z, a3.z};
            P[2] = (v2f){a1.y, a3.y}; P[3] = (v2f){a1.x, a3.x};
            P[4] = (v2f){a0.w, a2.w}; P[5] = (v2f){a0.z, a2.z};
            P[6] = (v2f){a0.y, a2.y}; P[7] = (v2f){a0.x, a2.x};
        }

        #pragma unroll
        for (int k = 0; k < 8; ++k) {
            const int off = (7 - k) * QROW;
            const float4 fa = *(const float4*)(qrow7 + off);      // fresh p=0..3
            const float4 fb = *(const float4*)(qrow7 + off + 4);  // fresh p=4..7
            const v2f* qsp = (const v2f*)(qsm + (k << 3));        // Qm broadcast
            const v2f qp[4] = {qsp[0], qsp[1], qsp[2], qsp[3]};
            const float fr[8] = {fa.x, fa.y, fa.z, fa.w, fb.x, fb.y, fb.z, fb.w};
            #pragma unroll
            for (int i = 0; i < 8; ++i) {
                const v2f q = qp[i >> 1];
                const int qh = i & 1;
                #pragma unroll
                for (int r = 0; r < 8; ++r) {
                    const int rho  = (r - i + 16) & 7;
                    const int swap = ((((r - i) & 8) ? 1 : 0) ^ (k & 1));
                    pkfma(A[r], q, P[rho], qh, swap);
                }
                // fresh slot sigma = (15-tau)&15: k even -> hi half, odd -> lo
                if ((k & 1) == 0) P[7 - i].y = fr[i];
                else              P[7 - i].x = fr[i];
            }
        }

        // ---- h-pair reduction, select half, store skewed partials ----
        float o[8];
        #pragma unroll
        for (int r = 0; r < 8; ++r) {
            float sx = A[r].x + __shfl_xor(A[r].x, 1, 64);
            float sy = A[r].y + __shfl_xor(A[r].y, 1, 64);
            o[r] = h ? sy : sx;         // t = 16J + 8h + r
        }
        *(float4*)(pwr)     = make_float4(o[0], o[1], o[2], o[3]);
        *(float4*)(pwr + 4) = make_float4(o[4], o[5], o[6], o[7]);
        __syncthreads();

        // ---- combine 4 wave partials, scale by DT, write back Q ----
        {
            float v0 = (partial[0][s0i] + partial[1][s0i])
                     + (partial[2][s0i] + partial[3][s0i]);
            float v1 = (partial[0][s1i] + partial[1][s1i])
                     + (partial[2][s1i] + partial[3][s1i]);
            Qs[tau0] = v0 * DTC;
            Qs[tau1] = v1 * DTC;
        }
        __syncthreads();

        if (tid == 0) {
            float qlast = Qs[TT - 1];
            float wgt = (n < NN - 1) ? (powers[(b * NN + n + 1) * LL + l] + 1.f)
                                     : 1.f;   // LAM term for n = 19
            lossCh += wgt * qlast;
        }
    }

    if (tid == 0) atomicAdd(out, lossCh);
}

extern "C" void kernel_launch(void* const* d_in, const int* in_sizes, int n_in,
                              void* d_out, int out_size, void* d_ws, size_t ws_size,
                              hipStream_t stream) {
    const float* pathloss = (const float*)d_in[0];
    const float* powers   = (const float*)d_in[1];
    float* outp = (float*)d_out;
    float* ws   = (float*)d_ws;

    hipMemsetAsync(d_out, 0, sizeof(float) * out_size, stream);
    prep_kernel<<<1, 64, 0, stream>>>(pathloss, ws);
    outage_kernel<<<BB * LL, 256, 0, stream>>>(powers, ws, outp);
}